// Round 1
// baseline (205.717 us; speedup 1.0000x reference)
//
#include <hip/hip_runtime.h>

#define BATCH 2
#define NPTS 16384
#define BLOCK 256
#define Q 4
#define QPB (BLOCK * Q)           // 1024 queries per block
#define QBLOCKS (NPTS / QPB)      // 16
#define CHUNKS 16
#define CHUNK (NPTS / CHUNKS)     // 1024 db points per block
#define TILE 256                  // LDS staging tile
#define THRESHOLD_F 33.33f

// ws layout: uint d2min[2 dirs][BATCH][NPTS]  (float bits, nonneg -> uint order == float order)

__global__ __launch_bounds__(BLOCK) void init_min_kernel(unsigned int* __restrict__ d2min) {
    int i = blockIdx.x * BLOCK + threadIdx.x;
    d2min[i] = 0x7F800000u;  // +inf
}

__global__ __launch_bounds__(BLOCK) void chamfer_min_kernel(
    const float* __restrict__ src, const float* __restrict__ tgt,
    unsigned int* __restrict__ d2min)
{
    const int bx  = blockIdx.x;          // [0, QBLOCKS*CHUNKS)
    const int b   = blockIdx.y;          // batch
    const int dir = blockIdx.z;          // 0: src->tgt, 1: tgt->src
    const int qb  = bx / CHUNKS;
    const int ck  = bx % CHUNKS;
    const int tid = threadIdx.x;

    const float* qptr = (dir == 0 ? src : tgt) + (size_t)b * NPTS * 3;
    const float* dptr = (dir == 0 ? tgt : src) + (size_t)b * NPTS * 3;
    unsigned int* mout = d2min + (size_t)(dir * BATCH + b) * NPTS;

    float qx[Q], qy[Q], qz[Q], m[Q];
#pragma unroll
    for (int i = 0; i < Q; i++) {
        int q = qb * QPB + i * BLOCK + tid;
        qx[i] = qptr[q * 3 + 0];
        qy[i] = qptr[q * 3 + 1];
        qz[i] = qptr[q * 3 + 2];
        m[i] = 3.4e38f;
    }

    __shared__ float4 tile[TILE];
    const int dbase = ck * CHUNK;

    for (int t = 0; t < CHUNK; t += TILE) {
        int j = dbase + t + tid;
        tile[tid] = make_float4(dptr[j * 3 + 0], dptr[j * 3 + 1], dptr[j * 3 + 2], 0.0f);
        __syncthreads();
#pragma unroll 4
        for (int jj = 0; jj < TILE; jj++) {
            float4 p = tile[jj];  // all lanes same address -> LDS broadcast, conflict-free
#pragma unroll
            for (int i = 0; i < Q; i++) {
                float dx = qx[i] - p.x;
                float dy = qy[i] - p.y;
                float dz = qz[i] - p.z;
                float d2 = fmaf(dz, dz, fmaf(dy, dy, dx * dx));
                m[i] = fminf(m[i], d2);
            }
        }
        __syncthreads();
    }

#pragma unroll
    for (int i = 0; i < Q; i++) {
        int q = qb * QPB + i * BLOCK + tid;
        atomicMin(&mout[q], __float_as_uint(m[i]));
    }
}

__global__ __launch_bounds__(BLOCK) void chamfer_reduce_kernel(
    const unsigned int* __restrict__ d2min, float* __restrict__ out)
{
    const int b = blockIdx.x;
    const unsigned int* m0 = d2min + (size_t)(0 * BATCH + b) * NPTS;
    const unsigned int* m1 = d2min + (size_t)(1 * BATCH + b) * NPTS;

    float s = 0.0f;
    for (int i = threadIdx.x; i < NPTS; i += BLOCK) {
        s += fminf(sqrtf(__uint_as_float(m0[i])), THRESHOLD_F);
        s += fminf(sqrtf(__uint_as_float(m1[i])), THRESHOLD_F);
    }
    // wave64 reduce
#pragma unroll
    for (int off = 32; off > 0; off >>= 1) s += __shfl_down(s, off, 64);

    __shared__ float ws[BLOCK / 64];
    if ((threadIdx.x & 63) == 0) ws[threadIdx.x >> 6] = s;
    __syncthreads();
    if (threadIdx.x == 0) {
        float t = 0.0f;
#pragma unroll
        for (int w = 0; w < BLOCK / 64; w++) t += ws[w];
        out[b] = t / (2.0f * NPTS);  // (mean_fwd + mean_bwd) / 2
    }
}

extern "C" void kernel_launch(void* const* d_in, const int* in_sizes, int n_in,
                              void* d_out, int out_size, void* d_ws, size_t ws_size,
                              hipStream_t stream) {
    const float* src = (const float*)d_in[0];
    const float* tgt = (const float*)d_in[1];
    float* out = (float*)d_out;
    unsigned int* d2min = (unsigned int*)d_ws;  // 2*BATCH*NPTS uints = 512 KiB

    init_min_kernel<<<(2 * BATCH * NPTS) / BLOCK, BLOCK, 0, stream>>>(d2min);

    dim3 grid(QBLOCKS * CHUNKS, BATCH, 2);
    chamfer_min_kernel<<<grid, BLOCK, 0, stream>>>(src, tgt, d2min);

    chamfer_reduce_kernel<<<BATCH, BLOCK, 0, stream>>>(d2min, out);
}

// Round 2
// 126.395 us; speedup vs baseline: 1.6276x; 1.6276x over previous
//
#include <hip/hip_runtime.h>

#define BATCH 2
#define NPTS 16384
#define BLOCK 256
#define Q 8
#define QPB (BLOCK * Q)            // 2048 src queries per block
#define QBLOCKS (NPTS / QPB)       // 8
#define CHUNKS 32
#define CHUNK (NPTS / CHUNKS)      // 512 tgt points per block
#define NSUB (CHUNK / 64)          // 8 subtiles of 64
#define THRESHOLD_F 33.33f
#define CSHIFT 128.0f              // positivity shift for col keys (|dot| <= ~75)

// ws layout: uint d2row[BATCH][NPTS] ; uint d2col[BATCH][NPTS]  (d^2 as float bits, nonneg)

__global__ __launch_bounds__(BLOCK) void init_kernel(unsigned int* __restrict__ ws,
                                                     float* __restrict__ out) {
    int i = blockIdx.x * BLOCK + threadIdx.x;
    ws[i] = 0x7F800000u;  // +inf
    if (i < BATCH) out[i] = 0.0f;
}

// One pass computes BOTH direction mins: rows (src->tgt) in registers,
// cols (tgt->src) via rotated conflict-free LDS atomics.
__global__ __launch_bounds__(BLOCK) void chamfer_sym_kernel(
    const float* __restrict__ src, const float* __restrict__ tgt,
    unsigned int* __restrict__ d2row, unsigned int* __restrict__ d2col)
{
    const int qb  = blockIdx.x / CHUNKS;
    const int ck  = blockIdx.x % CHUNKS;
    const int b   = blockIdx.y;
    const int tid = threadIdx.x;
    const int lane = tid & 63;

    const float* qptr = src + (size_t)b * NPTS * 3;
    const float* pptr = tgt + (size_t)b * NPTS * 3;

    // doubled subtiles: point j of subtile 'sub' lives at [sub*128+j] and [sub*128+j+64]
    __shared__ float4 tile[NSUB * 128];          // 16 KB  (x,y,z, hp=0.5*|p|^2)
    __shared__ unsigned int colmin_s[NSUB * 128]; // 4 KB   (doubled col keys, float bits)

    // --- stage chunk of tgt points (once per block) ---
    for (int k = tid; k < CHUNK; k += BLOCK) {
        int g = ck * CHUNK + k;
        float x = pptr[g * 3 + 0], y = pptr[g * 3 + 1], z = pptr[g * 3 + 2];
        float hp = 0.5f * fmaf(z, z, fmaf(y, y, x * x));
        float4 v = make_float4(x, y, z, hp);
        int sub = k >> 6, pos = k & 63;
        tile[sub * 128 + pos]      = v;
        tile[sub * 128 + pos + 64] = v;
    }
    for (int k = tid; k < NSUB * 128; k += BLOCK) colmin_s[k] = 0x7F800000u;

    // --- load queries (8 per thread) ---
    float qx[Q], qy[Q], qz[Q], hq[Q], m[Q];
#pragma unroll
    for (int i = 0; i < Q; i++) {
        int q = qb * QPB + i * BLOCK + tid;
        float x = qptr[q * 3 + 0], y = qptr[q * 3 + 1], z = qptr[q * 3 + 2];
        qx[i] = x; qy[i] = y; qz[i] = z;
        hq[i] = fmaf(0.5f, fmaf(z, z, fmaf(y, y, x * x)), CSHIFT); // 0.5|q|^2 + C
        m[i]  = 3.4e38f;
    }
    __syncthreads();

    // --- main loop: rotated gather, shared-dot row+col keys ---
    for (int sub = 0; sub < NSUB; ++sub) {
        const float4* tptr = &tile[sub * 128 + lane];
        unsigned int* cptr = &colmin_s[sub * 128 + lane];
#pragma unroll 16
        for (int s = 0; s < 64; ++s) {
            float4 p = tptr[s];   // ds_read_b128, immediate offset, conflict-free rotation
            float cmin;
#pragma unroll
            for (int i = 0; i < Q; i++) {
                float dot = fmaf(qz[i], p.z, fmaf(qy[i], p.y, qx[i] * p.x));
                m[i] = fminf(m[i], p.w - dot);          // row key: hp - dot
                float kc = hq[i] - dot;                 // col key: hq + C - dot (>0)
                cmin = (i == 0) ? kc : fminf(cmin, kc);
            }
            atomicMin(&cptr[s], __float_as_uint(cmin)); // distinct addr per lane
        }
    }

    // --- row flush ---
#pragma unroll
    for (int i = 0; i < Q; i++) {
        int q = qb * QPB + i * BLOCK + tid;
        float d2 = 2.0f * (m[i] + (hq[i] - CSHIFT));
        d2 = fmaxf(d2, 0.0f);
        atomicMin(&d2row[(size_t)b * NPTS + q], __float_as_uint(d2));
    }

    __syncthreads();

    // --- col flush: merge doubled slots, recover d^2 ---
    for (int k = tid; k < CHUNK; k += BLOCK) {
        int sub = k >> 6, pos = k & 63;
        unsigned int e = min(colmin_s[sub * 128 + pos], colmin_s[sub * 128 + pos + 64]);
        float kc = __uint_as_float(e);
        float hp = tile[sub * 128 + pos].w;
        float d2 = 2.0f * (kc - CSHIFT + hp);
        d2 = fmaxf(d2, 0.0f);
        atomicMin(&d2col[(size_t)b * NPTS + ck * CHUNK + k], __float_as_uint(d2));
    }
}

__global__ __launch_bounds__(BLOCK) void chamfer_reduce_kernel(
    const unsigned int* __restrict__ d2row, const unsigned int* __restrict__ d2col,
    float* __restrict__ out)
{
    const int b = blockIdx.y;
    const size_t base = (size_t)b * NPTS + blockIdx.x * (NPTS / 16);

    float s = 0.0f;
    for (int k = threadIdx.x; k < NPTS / 16; k += BLOCK) {
        s += fminf(sqrtf(__uint_as_float(d2row[base + k])), THRESHOLD_F);
        s += fminf(sqrtf(__uint_as_float(d2col[base + k])), THRESHOLD_F);
    }
#pragma unroll
    for (int off = 32; off > 0; off >>= 1) s += __shfl_down(s, off, 64);

    __shared__ float wsum[BLOCK / 64];
    if ((threadIdx.x & 63) == 0) wsum[threadIdx.x >> 6] = s;
    __syncthreads();
    if (threadIdx.x == 0) {
        float t = 0.0f;
#pragma unroll
        for (int w = 0; w < BLOCK / 64; w++) t += wsum[w];
        atomicAdd(&out[b], t * (1.0f / (2.0f * NPTS)));  // (mean_fwd+mean_bwd)/2
    }
}

extern "C" void kernel_launch(void* const* d_in, const int* in_sizes, int n_in,
                              void* d_out, int out_size, void* d_ws, size_t ws_size,
                              hipStream_t stream) {
    const float* src = (const float*)d_in[0];
    const float* tgt = (const float*)d_in[1];
    float* out = (float*)d_out;
    unsigned int* d2row = (unsigned int*)d_ws;                 // BATCH*NPTS uints
    unsigned int* d2col = d2row + (size_t)BATCH * NPTS;        // BATCH*NPTS uints

    init_kernel<<<(2 * BATCH * NPTS) / BLOCK, BLOCK, 0, stream>>>(d2row, out);

    dim3 grid(QBLOCKS * CHUNKS, BATCH);
    chamfer_sym_kernel<<<grid, BLOCK, 0, stream>>>(src, tgt, d2row, d2col);

    dim3 rgrid(16, BATCH);
    chamfer_reduce_kernel<<<rgrid, BLOCK, 0, stream>>>(d2row, d2col, out);
}